// Round 7
// baseline (86.643 us; speedup 1.0000x reference)
//
#include <hip/hip_runtime.h>
#include <math.h>

#define NTOK 16384   // B*S
#define DDIM 2048
#define NEXP 64
#define NKQ 8        // K split into 8 slices
#define KSLICE 256   // k per slice (8 ksteps of 32)
#define TPB 128      // tokens per gemm block (8 waves x 16)

typedef __attribute__((ext_vector_type(8))) short bf16x8;
typedef __attribute__((ext_vector_type(4))) float f32x4;

// ws layout (bytes):
//   [0, 516)          aux accumulators: cnt[64], Psum[64], zsum (zeroed per call)
//   [1024, 787456)    wp: packed W fragments [4 eg][64 ks][3 part][512 shorts]
//   [1MB, 1MB+32MB)   partial logits: [8 kq][16384 tok][64 exp] fp32

// ---- 3-way bf16 split: x ~= h + m + l, residual <= 2^-27 |x| ----
__device__ __forceinline__ unsigned short f2bf(float f) {
    unsigned int u = __builtin_bit_cast(unsigned int, f);
    u += 0x7fffu + ((u >> 16) & 1u);          // RNE to bf16
    return (unsigned short)(u >> 16);
}
__device__ __forceinline__ float bf2f(unsigned short s) {
    return __builtin_bit_cast(float, ((unsigned int)s) << 16);
}
__device__ __forceinline__ void split3(float x, unsigned short &h,
                                       unsigned short &m, unsigned short &l) {
    h = f2bf(x);
    float r1 = x - bf2f(h);    // exact (Sterbenz)
    m = f2bf(r1);
    float r2 = r1 - bf2f(m);   // exact
    l = f2bf(r2);
}

// ---- pack gate_w into B-fragment layout (validated, unchanged) ----
__global__ void k_wpack(const float* __restrict__ gw, unsigned short* __restrict__ wp) {
    int idx = blockIdx.x * 256 + threadIdx.x;   // 16384 threads
    int lane = idx & 63;
    int ks   = (idx >> 6) & 63;                 // global k-step (32 k each)
    int eg   = idx >> 12;                       // expert group 0..3
    int e  = eg * 16 + (lane & 15);
    int k0 = ks * 32 + (lane >> 4) * 8;
    const float* src = gw + (size_t)e * DDIM + k0;
    union { unsigned short s[8]; uint4 v; } H, M, L;
    #pragma unroll
    for (int j = 0; j < 8; ++j) split3(src[j], H.s[j], M.s[j], L.s[j]);
    size_t fb = (size_t)(eg * 64 + ks) * 1536 + lane * 8;   // shorts
    *(uint4*)(wp + fb)        = H.v;
    *(uint4*)(wp + fb + 512)  = M.v;
    *(uint4*)(wp + fb + 1024) = L.v;
}

// ---- phase 1: K-sliced GEMM; W staged in two 4-kstep halves (49 KB LDS ->
// 3 blocks/CU = 6 waves/SIMD); x streamed straight to registers.
__global__ __launch_bounds__(512, 4)
void k_gemm(const float* __restrict__ x, const unsigned short* __restrict__ wp,
            float* __restrict__ part) {
    // Ws: [4 eg][4 ks][3 part][1024 B] — one 4-kstep half of this block's slice
    __shared__ __align__(16) char Ws[49152];

    const int tid  = threadIdx.x;
    const int kq   = blockIdx.x & 7;            // k slice
    const int tok0 = (blockIdx.x >> 3) * TPB;   // token chunk base

    const int lane = tid & 63;
    const int wv   = tid >> 6;                  // 0..7: wave owns 16 tokens
    const int tau  = lane & 15;
    const int kap  = lane >> 4;

    // ---- x prefetch ring (4 ksteps): this lane's row/k-position
    const float* xb = x + (size_t)(tok0 + wv * 16 + tau) * DDIM
                        + kq * KSLICE + kap * 8;
    float4 xf[4][2];
    #pragma unroll
    for (int i = 0; i < 4; ++i) {
        xf[i][0] = *(const float4*)(xb + i * 32);
        xf[i][1] = *(const float4*)(xb + i * 32 + 4);
    }

    f32x4 acc[4];
    #pragma unroll
    for (int eg = 0; eg < 4; ++eg) acc[eg] = (f32x4){0.f, 0.f, 0.f, 0.f};

    for (int h = 0; h < 2; ++h) {
        if (h) __syncthreads();   // phase-0 LDS reads complete before overwrite
        // ---- stage W half h: per eg, 12288 contiguous bytes (ksteps h*4..h*4+3)
        {
            const char* wsrc = (const char*)wp + (size_t)(kq * 8 + h * 4) * 3072;
            #pragma unroll
            for (int eg = 0; eg < 4; ++eg) {
                const char* s = wsrc + (size_t)eg * 196608;   // eg stride 64*3072
                char* d = Ws + eg * 12288;
                #pragma unroll
                for (int r = 0; r < 2; ++r) {
                    int idx = r * 512 + tid;
                    if (idx < 768)
                        *(uint4*)(d + idx * 16) = *(const uint4*)(s + idx * 16);
                }
            }
        }
        __syncthreads();
        // ---- 4 MFMA k-steps on this half; refill x ring for phase 1
        #pragma unroll
        for (int ks = 0; ks < 4; ++ks) {
            float4 a = xf[ks][0], b = xf[ks][1];
            union U8 { unsigned short s[8]; bf16x8 v; };
            U8 Ah, Am, Al;
            float in[8] = {a.x, a.y, a.z, a.w, b.x, b.y, b.z, b.w};
            #pragma unroll
            for (int j = 0; j < 8; ++j) split3(in[j], Ah.s[j], Am.s[j], Al.s[j]);

            if (h == 0) {
                xf[ks][0] = *(const float4*)(xb + 128 + ks * 32);
                xf[ks][1] = *(const float4*)(xb + 128 + ks * 32 + 4);
            }

            #pragma unroll
            for (int eg = 0; eg < 4; ++eg) {
                const char* wb = Ws + eg * 12288 + ks * 3072 + lane * 16;
                bf16x8 Bh = *(const bf16x8*)(wb);
                bf16x8 Bm = *(const bf16x8*)(wb + 1024);
                bf16x8 Bl = *(const bf16x8*)(wb + 2048);
                acc[eg] = __builtin_amdgcn_mfma_f32_16x16x32_bf16(Ah.v, Bh, acc[eg], 0, 0, 0);
                acc[eg] = __builtin_amdgcn_mfma_f32_16x16x32_bf16(Ah.v, Bm, acc[eg], 0, 0, 0);
                acc[eg] = __builtin_amdgcn_mfma_f32_16x16x32_bf16(Am.v, Bh, acc[eg], 0, 0, 0);
                acc[eg] = __builtin_amdgcn_mfma_f32_16x16x32_bf16(Ah.v, Bl, acc[eg], 0, 0, 0);
                acc[eg] = __builtin_amdgcn_mfma_f32_16x16x32_bf16(Al.v, Bh, acc[eg], 0, 0, 0);
                acc[eg] = __builtin_amdgcn_mfma_f32_16x16x32_bf16(Am.v, Bm, acc[eg], 0, 0, 0);
            }
        }
    }

    // ---- store partials: part[kq][tok][e]; C/D: col=tau(exp), row=kap*4+j(tok)
    float* pb = part + ((size_t)kq * NTOK + tok0 + wv * 16) * 64;
    #pragma unroll
    for (int eg = 0; eg < 4; ++eg)
        #pragma unroll
        for (int j = 0; j < 4; ++j)
            pb[(kap * 4 + j) * 64 + eg * 16 + tau] = acc[eg][j];
}

// ---- phase 2: deterministic K-reduction + softmax / top-2 / aux ----
__global__ __launch_bounds__(256)
void k_reduce(const float* __restrict__ part, float* __restrict__ out,
              float* __restrict__ gcnt, float* __restrict__ gP,
              float* __restrict__ gz) {
    __shared__ float Ps[NEXP], Cnt[NEXP], Zs;
    const int tid = threadIdx.x;
    if (tid < NEXP) { Ps[tid] = 0.f; Cnt[tid] = 0.f; }
    if (tid == 0) Zs = 0.f;
    __syncthreads();   // init must complete before any wave's atomicAdd

    const int lane = tid & 63;
    const int wv   = tid >> 6;
    const int t0   = blockIdx.x * 16 + wv * 4;   // 4 tokens per wave

    // load all partials for 4 tokens (fully static indexing)
    float v[4][8];
    #pragma unroll
    for (int i = 0; i < 4; ++i)
        #pragma unroll
        for (int q = 0; q < 8; ++q)
            v[i][q] = part[((size_t)q * NTOK + t0 + i) * 64 + lane];

    float Pacc = 0.f, zacc = 0.f;
    #pragma unroll
    for (int i = 0; i < 4; ++i) {
        // fixed-order pairwise sum over the 8 k-slices (deterministic)
        float l = ((v[i][0] + v[i][1]) + (v[i][2] + v[i][3]))
                + ((v[i][4] + v[i][5]) + (v[i][6] + v[i][7]));
        float mx = l;
        #pragma unroll
        for (int off = 32; off > 0; off >>= 1) mx = fmaxf(mx, __shfl_xor(mx, off));
        float s = expf(l - mx);
        float sum = s;
        #pragma unroll
        for (int off = 32; off > 0; off >>= 1) sum += __shfl_xor(sum, off);
        Pacc += s / sum;

        unsigned long long b1 = __ballot(l == mx);
        int i1 = __ffsll(b1) - 1;              // lowest index on ties
        float l2 = (lane == i1) ? -INFINITY : l;
        float m2 = l2;
        #pragma unroll
        for (int off = 32; off > 0; off >>= 1) m2 = fmaxf(m2, __shfl_xor(m2, off));
        unsigned long long b2 = __ballot(l2 == m2);
        int i2 = __ffsll(b2) - 1;

        if (lane == 0) {
            float s2  = expf(m2 - mx);
            float inv = 1.f / (1.f + s2);
            int gt = t0 + i;
            ((float2*)out)[gt]              = make_float2((float)i1, (float)i2);
            ((float2*)(out + 2 * NTOK))[gt] = make_float2(inv, s2 * inv);
            atomicAdd(&Cnt[i1], 1.f);
            atomicAdd(&Cnt[i2], 1.f);
            float lse = mx + logf(sum);
            zacc += lse * lse;
        }
    }
    atomicAdd(&Ps[lane], Pacc);
    if (lane == 0) atomicAdd(&Zs, zacc);
    __syncthreads();

    if (tid < NEXP) {
        atomicAdd(&gcnt[tid], Cnt[tid]);
        atomicAdd(&gP[tid],   Ps[tid]);
    }
    if (tid == 0) atomicAdd(gz, Zs);
}

__global__ void k_final(const float* __restrict__ ws, float* __restrict__ out) {
    int lane = threadIdx.x;  // 64 threads
    float v = ws[lane] * ws[64 + lane];   // cnt_e * Psum_e
    #pragma unroll
    for (int off = 32; off > 0; off >>= 1) v += __shfl_xor(v, off);
    if (lane == 0) {
        float bal = 64.f * v / (32768.f * 16384.f);
        float z   = ws[128] / 16384.f;
        out[4 * NTOK] = 0.01f * bal + 0.001f * z;
    }
}

extern "C" void kernel_launch(void* const* d_in, const int* in_sizes, int n_in,
                              void* d_out, int out_size, void* d_ws, size_t ws_size,
                              hipStream_t stream) {
    const float* x  = (const float*)d_in[0];
    const float* gw = (const float*)d_in[1];
    float* out = (float*)d_out;
    float* wsf = (float*)d_ws;
    unsigned short* wp = (unsigned short*)((char*)d_ws + 1024);
    float* part = (float*)((char*)d_ws + (1 << 20));

    hipMemsetAsync(d_ws, 0, 516, stream);   // zero aux accumulators
    k_wpack<<<64, 256, 0, stream>>>(gw, wp);
    k_gemm<<<NKQ * (NTOK / TPB), 512, 0, stream>>>(x, wp, part);
    k_reduce<<<NTOK / 16, 256, 0, stream>>>(part, out, wsf, wsf + 64, wsf + 128);
    k_final<<<1, 64, 0, stream>>>(wsf, out);
}